// Round 7
// baseline (185.642 us; speedup 1.0000x reference)
//
#include <hip/hip_runtime.h>

#define N_NODES 4096
#define KNN 9
#define CAPS 128                // survivor capacity per row (2 per lane)
#define CAPE 32                 // max edges per node in strided elist
#define THRESH 0.99f

__device__ __forceinline__ bool vi_greater(float av, int aj, float bv, int bj) {
  // order: larger value first; ties -> smaller index first (matches lax.top_k)
  return (av > bv) || (av == bv && aj < bj);
}

// Zero the per-node edge counters (custom kernel: rocclr fill costs ~40us).
__global__ void zero_kernel(int* __restrict__ cur) {
  int i = blockIdx.x * blockDim.x + threadIdx.x;
  if (i < N_NODES) cur[i] = 0;
}

// Top-k: one wave per row, 4 waves/block. Branchless ballot-compaction of
// survivors (> THRESH, off-diagonal) into per-wave LDS, then 8 wave-argmax
// rounds (9th slot is always the center node). Exact full-row fallback.
// Lanes 0..8 then write idx and append this edge to each member's strided
// elist (cur doubles as the node degree DV).
__global__ __launch_bounds__(256) void topk_kernel(const float* __restrict__ dis,
                                                   int* __restrict__ idx,
                                                   int* __restrict__ cur,
                                                   int* __restrict__ elist) {
  __shared__ float sval[4 * CAPS];
  __shared__ int   sidx[4 * CAPS];
  const int lane = threadIdx.x & 63;
  const int wv = threadIdx.x >> 6;
  const int row = blockIdx.x * 4 + wv;
  const float4* r4 = reinterpret_cast<const float4*>(dis + (size_t)row * N_NODES);
  float* wval = sval + wv * CAPS;
  int*   widx = sidx + wv * CAPS;
  const unsigned long long lmask = (1ull << lane) - 1;

  // phase 1: branch-free survivor compaction
  int n = 0;
#pragma unroll 4
  for (int t = 0; t < 16; ++t) {
    float4 f4 = r4[t * 64 + lane];
    float vals[4] = {f4.x, f4.y, f4.z, f4.w};
    int cb = (t * 64 + lane) * 4;
#pragma unroll
    for (int q = 0; q < 4; ++q) {
      int cc = cb + q;
      bool pred = (vals[q] > THRESH) && (cc != row);
      unsigned long long m = __ballot(pred);
      if (pred) {
        int p = n + __popcll(m & lmask);
        if (p < CAPS) { wval[p] = vals[q]; widx[p] = cc; }
      }
      n += __popcll(m);
    }
  }
  __syncthreads();

  int outj[KNN];
  if (n >= 8 && n <= CAPS) {
    // fast path: top-8 of survivors; slot 8 is the center (diagonal zeroed in
    // the reference can never beat >=8 survivors above 0.99).
    float v0 = -3.0e38f, v1 = -3.0e38f;
    int c0 = 0x7fffffff, c1 = 0x7fffffff;
    if (lane < n)      { v0 = wval[lane];      c0 = widx[lane]; }
    if (lane + 64 < n) { v1 = wval[lane + 64]; c1 = widx[lane + 64]; }
#pragma unroll
    for (int rnd = 0; rnd < 8; ++rnd) {
      bool first = vi_greater(v0, c0, v1, c1);
      float mv = first ? v0 : v1;
      int   mc = first ? c0 : c1;
#pragma unroll
      for (int d = 1; d < 64; d <<= 1) {
        float ov = __shfl_xor(mv, d);
        int   oc = __shfl_xor(mc, d);
        if (vi_greater(ov, oc, mv, mc)) { mv = ov; mc = oc; }
      }
      outj[rnd] = mc;
      if (c0 == mc) v0 = -3.3e38f;
      if (c1 == mc) v1 = -3.3e38f;
    }
    outj[8] = row;
  } else {
    // exact fallback: full-row per-lane sorted top-9 + 9 extraction rounds
    const float* r = dis + (size_t)row * N_NODES;
    float v[9]; int ji[9];
#pragma unroll
    for (int t = 0; t < 9; ++t) { v[t] = -3.0e38f; ji[t] = 0x7fffffff; }
    for (int t = 0; t < 64; ++t) {
      int cc = t * 64 + lane;
      float val = (cc == row) ? 0.0f : r[cc];
      if (vi_greater(val, cc, v[8], ji[8])) {
        v[8] = val; ji[8] = cc;
#pragma unroll
        for (int s = 8; s > 0; --s) {
          if (vi_greater(v[s], ji[s], v[s-1], ji[s-1])) {
            float tv = v[s]; v[s] = v[s-1]; v[s-1] = tv;
            int tj = ji[s]; ji[s] = ji[s-1]; ji[s-1] = tj;
          }
        }
      }
    }
    bool has_center = false;
#pragma unroll
    for (int rnd = 0; rnd < 9; ++rnd) {
      float mv = v[0]; int mj = ji[0];
#pragma unroll
      for (int d = 1; d < 64; d <<= 1) {
        float ov = __shfl_xor(mv, d);
        int   oj = __shfl_xor(mj, d);
        if (vi_greater(ov, oj, mv, mj)) { mv = ov; mj = oj; }
      }
      outj[rnd] = mj;
      has_center = has_center || (mj == row);
      if (ji[0] == mj) {
#pragma unroll
        for (int s = 0; s < 8; ++s) { v[s] = v[s+1]; ji[s] = ji[s+1]; }
        v[8] = -3.0e38f; ji[8] = 0x7fffffff;
      }
    }
    if (!has_center) outj[8] = row;
  }

  // lanes 0..8: write idx and append edge `row` to member outj[lane]'s list.
  if (lane < KNN) {
    int j = outj[lane];
    idx[row * KNN + lane] = j;
    int p = atomicAdd(&cur[j], 1);
    if (p < CAPE) elist[j * CAPE + p] = row;
  }
}

// Stage A: Z[e,f] = (1/9) * sum_j DV[idx[e][j]]^-1/2 * Y[idx[e][j], f]
template<int F>
__global__ __launch_bounds__(F) void edge_gather(const float* __restrict__ Y,
                                                 const int* __restrict__ idx,
                                                 const int* __restrict__ DV,
                                                 float* __restrict__ Z) {
  __shared__ int er[KNN];
  __shared__ float ew[KNN];
  int e = blockIdx.x;
  if (threadIdx.x < KNN) {
    int r = idx[e * KNN + threadIdx.x];
    er[threadIdx.x] = r;
    ew[threadIdx.x] = rsqrtf((float)DV[r]);
  }
  __syncthreads();
  int f = threadIdx.x;
  float acc = 0.f;
#pragma unroll
  for (int j = 0; j < KNN; ++j)
    acc = fmaf(ew[j], Y[(size_t)er[j] * F + f], acc);
  Z[(size_t)e * F + f] = acc * (1.0f / 9.0f);
}

// Final stage B: out[i,f] = relu(DV[i]^-1/2 * sum_{e in elist[i]} Z[e,f])
template<int F>
__global__ __launch_bounds__(F) void node_gather(const float* __restrict__ Z,
                                                 const int* __restrict__ elist,
                                                 const int* __restrict__ DV,
                                                 float* __restrict__ out) {
  int i = blockIdx.x;
  int f = threadIdx.x;
  int cnt = DV[i]; if (cnt > CAPE) cnt = CAPE;
  float acc = 0.f;
  for (int t = 0; t < cnt; ++t)
    acc += Z[(size_t)elist[i * CAPE + t] * F + f];
  out[(size_t)i * F + f] = fmaxf(acc * rsqrtf((float)DV[i]), 0.f);
}

// Fused stage B + GEMM: per block, gather ROWS=8 H rows (width 128, relu'd)
// into LDS, then P = H @ W + bias. Row-iteration addressing is wave-uniform
// (elist/DV broadcast), Z reads fully coalesced. Optionally writes H (x1out).
template<int FO, bool WRITE_H>
__global__ __launch_bounds__(FO) void node_gemm(const float* __restrict__ Z,
                                                const int* __restrict__ elist,
                                                const int* __restrict__ DV,
                                                const float* __restrict__ W,
                                                const float* __restrict__ bias,
                                                float* __restrict__ P,
                                                float* __restrict__ Hout) {
  constexpr int KD = 128;
  constexpr int ROWS = 8;
  __shared__ float ylds[ROWS * KD];
  int m0 = blockIdx.x * ROWS;
  for (int cell = threadIdx.x; cell < ROWS * KD; cell += FO) {
    int rr = cell >> 7, f = cell & 127;
    int i = m0 + rr;
    int cnt = DV[i]; if (cnt > CAPE) cnt = CAPE;
    float acc = 0.f;
    for (int t = 0; t < cnt; ++t)
      acc += Z[(size_t)elist[i * CAPE + t] * KD + f];
    acc = fmaxf(acc * rsqrtf((float)DV[i]), 0.f);
    ylds[cell] = acc;
    if (WRITE_H) Hout[(size_t)i * KD + f] = acc;
  }
  __syncthreads();
  int f = threadIdx.x;
  float acc[ROWS];
#pragma unroll
  for (int rr = 0; rr < ROWS; ++rr) acc[rr] = 0.f;
  for (int k = 0; k < KD; k += 4) {
    float w0 = W[(size_t)(k + 0) * FO + f];
    float w1 = W[(size_t)(k + 1) * FO + f];
    float w2 = W[(size_t)(k + 2) * FO + f];
    float w3 = W[(size_t)(k + 3) * FO + f];
#pragma unroll
    for (int rr = 0; rr < ROWS; ++rr) {
      float4 y = *reinterpret_cast<const float4*>(&ylds[rr * KD + k]);
      acc[rr] = fmaf(y.x, w0, fmaf(y.y, w1, fmaf(y.z, w2, fmaf(y.w, w3, acc[rr]))));
    }
  }
  float bb = bias[f];
#pragma unroll
  for (int rr = 0; rr < ROWS; ++rr)
    P[(size_t)(m0 + rr) * FO + f] = acc[rr] + bb;
}

// Dense P = Y @ W + bias ; ROWS rows per block, FO threads (one output col
// each). COPY: also write the staged Y rows to xcopy (x passthrough output).
template<int KD, int FO, int ROWS, bool COPY>
__global__ __launch_bounds__(FO) void gemm_bias(const float* __restrict__ Y,
                                                const float* __restrict__ W,
                                                const float* __restrict__ bias,
                                                float* __restrict__ P,
                                                float* __restrict__ xcopy) {
  __shared__ float ylds[ROWS * KD];
  int m0 = blockIdx.x * ROWS;
  for (int t = threadIdx.x; t < ROWS * KD / 4; t += FO) {
    float4 y4 = reinterpret_cast<const float4*>(Y + (size_t)m0 * KD)[t];
    reinterpret_cast<float4*>(ylds)[t] = y4;
    if (COPY) reinterpret_cast<float4*>(xcopy + (size_t)m0 * KD)[t] = y4;
  }
  __syncthreads();
  int f = threadIdx.x;
  float acc[ROWS];
#pragma unroll
  for (int rr = 0; rr < ROWS; ++rr) acc[rr] = 0.f;
  for (int k = 0; k < KD; k += 4) {
    float w0 = W[(size_t)(k + 0) * FO + f];
    float w1 = W[(size_t)(k + 1) * FO + f];
    float w2 = W[(size_t)(k + 2) * FO + f];
    float w3 = W[(size_t)(k + 3) * FO + f];
#pragma unroll
    for (int rr = 0; rr < ROWS; ++rr) {
      float4 y = *reinterpret_cast<const float4*>(&ylds[rr * KD + k]);
      acc[rr] = fmaf(y.x, w0, fmaf(y.y, w1, fmaf(y.z, w2, fmaf(y.w, w3, acc[rr]))));
    }
  }
  float bb = bias[f];
#pragma unroll
  for (int rr = 0; rr < ROWS; ++rr)
    P[(size_t)(m0 + rr) * FO + f] = acc[rr] + bb;
}

extern "C" void kernel_launch(void* const* d_in, const int* in_sizes, int n_in,
                              void* d_out, int out_size, void* d_ws, size_t ws_size,
                              hipStream_t stream) {
  const float* x   = (const float*)d_in[0];
  const float* adj = (const float*)d_in[1];
  const float* W10 = (const float*)d_in[2];
  const float* b10 = (const float*)d_in[3];
  const float* W11 = (const float*)d_in[4];
  const float* b11 = (const float*)d_in[5];
  const float* W20 = (const float*)d_in[6];
  const float* b20 = (const float*)d_in[7];
  const float* W21 = (const float*)d_in[8];
  const float* b21 = (const float*)d_in[9];
  float* out = (float*)d_out;

  char* w = (char*)d_ws;
  int*   idx   = (int*)(w + 0);            // 147456
  int*   cur   = (int*)(w + 147456);       // 16384  (doubles as DV)
  int*   elist = (int*)(w + 163840);       // 4096*32*4 = 524288
  float* bufP  = (float*)(w + 688128);     // 4 MB
  float* bufZ  = (float*)(w + 4882432);    // 4 MB

  float* x1out = out + (size_t)N_NODES * 256;
  float* x2out = out + (size_t)N_NODES * 256 + (size_t)N_NODES * 128;

  // hypergraph construction (elist built inside topk; cur == DV afterwards)
  zero_kernel<<<16, 256, 0, stream>>>(cur);
  topk_kernel<<<N_NODES / 4, 256, 0, stream>>>(adj, idx, cur, elist);

  // layer 1 (gemm1 also emits the out=x passthrough)
  gemm_bias<256, 128, 8, true><<<N_NODES / 8, 128, 0, stream>>>(x, W10, b10, bufP, out);
  edge_gather<128><<<N_NODES, 128, 0, stream>>>(bufP, idx, cur, bufZ);
  node_gemm<128, false><<<N_NODES / 8, 128, 0, stream>>>(bufZ, elist, cur,
                                                         W11, b11, bufP, nullptr);
  edge_gather<128><<<N_NODES, 128, 0, stream>>>(bufP, idx, cur, bufZ);
  // x1 = relu(node gather); fused with layer-2 first GEMM, also writes x1out
  node_gemm<128, true><<<N_NODES / 8, 128, 0, stream>>>(bufZ, elist, cur,
                                                        W20, b20, bufP, x1out);
  // layer 2
  edge_gather<128><<<N_NODES, 128, 0, stream>>>(bufP, idx, cur, bufZ);
  node_gemm<256, false><<<N_NODES / 8, 256, 0, stream>>>(bufZ, elist, cur,
                                                         W21, b21, bufP, nullptr);
  edge_gather<256><<<N_NODES, 256, 0, stream>>>(bufP, idx, cur, bufZ);
  node_gather<256><<<N_NODES, 256, 0, stream>>>(bufZ, elist, cur, x2out);
}

// Round 8
// 132.038 us; speedup vs baseline: 1.4060x; 1.4060x over previous
//
#include <hip/hip_runtime.h>

#define N_NODES 4096
#define KNN 9
#define CAPS 128                // survivor capacity per row (2 per lane)
#define CAPE 32                 // max edges per node in strided elist
#define THRESH 0.99f

__device__ __forceinline__ bool vi_greater(float av, int aj, float bv, int bj) {
  // order: larger value first; ties -> smaller index first (matches lax.top_k)
  return (av > bv) || (av == bv && aj < bj);
}

// Zero the per-node edge counters (custom kernel: rocclr fill costs ~40us).
__global__ void zero_kernel(int* __restrict__ cur) {
  int i = blockIdx.x * blockDim.x + threadIdx.x;
  if (i < N_NODES) cur[i] = 0;
}

// Top-k: one wave per row, 4 waves/block. Branchless ballot-compaction of
// survivors (> THRESH, off-diagonal) into per-wave LDS, then 8 wave-argmax
// rounds (9th slot is always the center node). Exact full-row fallback.
// Lanes 0..8 then write idx and append this edge to each member's strided
// elist (cur doubles as the node degree DV).
__global__ __launch_bounds__(256) void topk_kernel(const float* __restrict__ dis,
                                                   int* __restrict__ idx,
                                                   int* __restrict__ cur,
                                                   int* __restrict__ elist) {
  __shared__ float sval[4 * CAPS];
  __shared__ int   sidx[4 * CAPS];
  const int lane = threadIdx.x & 63;
  const int wv = threadIdx.x >> 6;
  const int row = blockIdx.x * 4 + wv;
  const float4* r4 = reinterpret_cast<const float4*>(dis + (size_t)row * N_NODES);
  float* wval = sval + wv * CAPS;
  int*   widx = sidx + wv * CAPS;
  const unsigned long long lmask = (1ull << lane) - 1;

  // phase 1: branch-free survivor compaction
  int n = 0;
#pragma unroll 4
  for (int t = 0; t < 16; ++t) {
    float4 f4 = r4[t * 64 + lane];
    float vals[4] = {f4.x, f4.y, f4.z, f4.w};
    int cb = (t * 64 + lane) * 4;
#pragma unroll
    for (int q = 0; q < 4; ++q) {
      int cc = cb + q;
      bool pred = (vals[q] > THRESH) && (cc != row);
      unsigned long long m = __ballot(pred);
      if (pred) {
        int p = n + __popcll(m & lmask);
        if (p < CAPS) { wval[p] = vals[q]; widx[p] = cc; }
      }
      n += __popcll(m);
    }
  }
  __syncthreads();

  int outj[KNN];
  if (n >= 8 && n <= CAPS) {
    // fast path: top-8 of survivors; slot 8 is the center (diagonal zeroed in
    // the reference can never beat >=8 survivors above 0.99).
    float v0 = -3.0e38f, v1 = -3.0e38f;
    int c0 = 0x7fffffff, c1 = 0x7fffffff;
    if (lane < n)      { v0 = wval[lane];      c0 = widx[lane]; }
    if (lane + 64 < n) { v1 = wval[lane + 64]; c1 = widx[lane + 64]; }
#pragma unroll
    for (int rnd = 0; rnd < 8; ++rnd) {
      bool first = vi_greater(v0, c0, v1, c1);
      float mv = first ? v0 : v1;
      int   mc = first ? c0 : c1;
#pragma unroll
      for (int d = 1; d < 64; d <<= 1) {
        float ov = __shfl_xor(mv, d);
        int   oc = __shfl_xor(mc, d);
        if (vi_greater(ov, oc, mv, mc)) { mv = ov; mc = oc; }
      }
      outj[rnd] = mc;
      if (c0 == mc) v0 = -3.3e38f;
      if (c1 == mc) v1 = -3.3e38f;
    }
    outj[8] = row;
  } else {
    // exact fallback: full-row per-lane sorted top-9 + 9 extraction rounds
    const float* r = dis + (size_t)row * N_NODES;
    float v[9]; int ji[9];
#pragma unroll
    for (int t = 0; t < 9; ++t) { v[t] = -3.0e38f; ji[t] = 0x7fffffff; }
    for (int t = 0; t < 64; ++t) {
      int cc = t * 64 + lane;
      float val = (cc == row) ? 0.0f : r[cc];
      if (vi_greater(val, cc, v[8], ji[8])) {
        v[8] = val; ji[8] = cc;
#pragma unroll
        for (int s = 8; s > 0; --s) {
          if (vi_greater(v[s], ji[s], v[s-1], ji[s-1])) {
            float tv = v[s]; v[s] = v[s-1]; v[s-1] = tv;
            int tj = ji[s]; ji[s] = ji[s-1]; ji[s-1] = tj;
          }
        }
      }
    }
    bool has_center = false;
#pragma unroll
    for (int rnd = 0; rnd < 9; ++rnd) {
      float mv = v[0]; int mj = ji[0];
#pragma unroll
      for (int d = 1; d < 64; d <<= 1) {
        float ov = __shfl_xor(mv, d);
        int   oj = __shfl_xor(mj, d);
        if (vi_greater(ov, oj, mv, mj)) { mv = ov; mj = oj; }
      }
      outj[rnd] = mj;
      has_center = has_center || (mj == row);
      if (ji[0] == mj) {
#pragma unroll
        for (int s = 0; s < 8; ++s) { v[s] = v[s+1]; ji[s] = ji[s+1]; }
        v[8] = -3.0e38f; ji[8] = 0x7fffffff;
      }
    }
    if (!has_center) outj[8] = row;
  }

  // lanes 0..8: write idx and append edge `row` to member outj[lane]'s list.
  if (lane < KNN) {
    int j = outj[lane];
    idx[row * KNN + lane] = j;
    int p = atomicAdd(&cur[j], 1);
    if (p < CAPE) elist[j * CAPE + p] = row;
  }
}

// Stage A: Z[e,f] = (1/9) * sum_j DV[idx[e][j]]^-1/2 * Y[idx[e][j], f]
template<int F>
__global__ __launch_bounds__(F) void edge_gather(const float* __restrict__ Y,
                                                 const int* __restrict__ idx,
                                                 const int* __restrict__ DV,
                                                 float* __restrict__ Z) {
  __shared__ int er[KNN];
  __shared__ float ew[KNN];
  int e = blockIdx.x;
  if (threadIdx.x < KNN) {
    int r = idx[e * KNN + threadIdx.x];
    er[threadIdx.x] = r;
    ew[threadIdx.x] = rsqrtf((float)DV[r]);
  }
  __syncthreads();
  int f = threadIdx.x;
  float acc = 0.f;
#pragma unroll
  for (int j = 0; j < KNN; ++j)
    acc = fmaf(ew[j], Y[(size_t)er[j] * F + f], acc);
  Z[(size_t)e * F + f] = acc * (1.0f / 9.0f);
}

// Final stage B: out[i,f] = relu(DV[i]^-1/2 * sum_{e in elist[i]} Z[e,f])
template<int F>
__global__ __launch_bounds__(F) void node_gather(const float* __restrict__ Z,
                                                 const int* __restrict__ elist,
                                                 const int* __restrict__ DV,
                                                 float* __restrict__ out) {
  int i = blockIdx.x;
  int f = threadIdx.x;
  int cnt = DV[i]; if (cnt > CAPE) cnt = CAPE;
  float acc = 0.f;
  for (int t = 0; t < cnt; ++t)
    acc += Z[(size_t)elist[i * CAPE + t] * F + f];
  out[(size_t)i * F + f] = fmaxf(acc * rsqrtf((float)DV[i]), 0.f);
}

// Fused stage B + GEMM, occupancy-fixed: ROWS=4, 256 threads, 1024 blocks
// (16 waves/CU vs R7's 4). Gather: 512 cells, 2/thread, 9 independent loads
// each. GEMM: column-split — FO=128: thread-half owns 2 rows; FO=256:
// thread owns all 4 rows. Optionally writes H (x1 output).
template<int FO, bool WRITE_H>
__global__ __launch_bounds__(256) void node_gemm(const float* __restrict__ Z,
                                                 const int* __restrict__ elist,
                                                 const int* __restrict__ DV,
                                                 const float* __restrict__ W,
                                                 const float* __restrict__ bias,
                                                 float* __restrict__ P,
                                                 float* __restrict__ Hout) {
  constexpr int KD = 128;
  constexpr int ROWS = 4;
  constexpr int RPT = (FO == 128) ? 2 : 4;   // rows per thread
  __shared__ float ylds[ROWS * KD];
  int m0 = blockIdx.x * ROWS;
#pragma unroll
  for (int c0 = 0; c0 < ROWS * KD; c0 += 256) {
    int cell = c0 + threadIdx.x;
    int rr = cell >> 7, f = cell & 127;
    int i = m0 + rr;
    int cnt = DV[i]; if (cnt > CAPE) cnt = CAPE;
    float acc = 0.f;
    for (int t = 0; t < cnt; ++t)
      acc += Z[(size_t)elist[i * CAPE + t] * KD + f];
    acc = fmaxf(acc * rsqrtf((float)DV[i]), 0.f);
    ylds[cell] = acc;
    if (WRITE_H) Hout[(size_t)i * KD + f] = acc;
  }
  __syncthreads();
  const int f  = (FO == 128) ? (threadIdx.x & 127) : threadIdx.x;
  const int rb = (FO == 128) ? ((threadIdx.x >> 7) * 2) : 0;
  float acc[RPT];
#pragma unroll
  for (int rr = 0; rr < RPT; ++rr) acc[rr] = 0.f;
  for (int k = 0; k < KD; k += 4) {
    float w0 = W[(size_t)(k + 0) * FO + f];
    float w1 = W[(size_t)(k + 1) * FO + f];
    float w2 = W[(size_t)(k + 2) * FO + f];
    float w3 = W[(size_t)(k + 3) * FO + f];
#pragma unroll
    for (int rr = 0; rr < RPT; ++rr) {
      float4 y = *reinterpret_cast<const float4*>(&ylds[(rb + rr) * KD + k]);
      acc[rr] = fmaf(y.x, w0, fmaf(y.y, w1, fmaf(y.z, w2, fmaf(y.w, w3, acc[rr]))));
    }
  }
  float bb = bias[f];
#pragma unroll
  for (int rr = 0; rr < RPT; ++rr)
    P[(size_t)(m0 + rb + rr) * FO + f] = acc[rr] + bb;
}

// Dense P = Y @ W + bias ; ROWS rows per block, FO threads (one output col
// each). COPY: also write the staged Y rows to xcopy (x passthrough output).
template<int KD, int FO, int ROWS, bool COPY>
__global__ __launch_bounds__(FO) void gemm_bias(const float* __restrict__ Y,
                                                const float* __restrict__ W,
                                                const float* __restrict__ bias,
                                                float* __restrict__ P,
                                                float* __restrict__ xcopy) {
  __shared__ float ylds[ROWS * KD];
  int m0 = blockIdx.x * ROWS;
  for (int t = threadIdx.x; t < ROWS * KD / 4; t += FO) {
    float4 y4 = reinterpret_cast<const float4*>(Y + (size_t)m0 * KD)[t];
    reinterpret_cast<float4*>(ylds)[t] = y4;
    if (COPY) reinterpret_cast<float4*>(xcopy + (size_t)m0 * KD)[t] = y4;
  }
  __syncthreads();
  int f = threadIdx.x;
  float acc[ROWS];
#pragma unroll
  for (int rr = 0; rr < ROWS; ++rr) acc[rr] = 0.f;
  for (int k = 0; k < KD; k += 4) {
    float w0 = W[(size_t)(k + 0) * FO + f];
    float w1 = W[(size_t)(k + 1) * FO + f];
    float w2 = W[(size_t)(k + 2) * FO + f];
    float w3 = W[(size_t)(k + 3) * FO + f];
#pragma unroll
    for (int rr = 0; rr < ROWS; ++rr) {
      float4 y = *reinterpret_cast<const float4*>(&ylds[rr * KD + k]);
      acc[rr] = fmaf(y.x, w0, fmaf(y.y, w1, fmaf(y.z, w2, fmaf(y.w, w3, acc[rr]))));
    }
  }
  float bb = bias[f];
#pragma unroll
  for (int rr = 0; rr < ROWS; ++rr)
    P[(size_t)(m0 + rr) * FO + f] = acc[rr] + bb;
}

extern "C" void kernel_launch(void* const* d_in, const int* in_sizes, int n_in,
                              void* d_out, int out_size, void* d_ws, size_t ws_size,
                              hipStream_t stream) {
  const float* x   = (const float*)d_in[0];
  const float* adj = (const float*)d_in[1];
  const float* W10 = (const float*)d_in[2];
  const float* b10 = (const float*)d_in[3];
  const float* W11 = (const float*)d_in[4];
  const float* b11 = (const float*)d_in[5];
  const float* W20 = (const float*)d_in[6];
  const float* b20 = (const float*)d_in[7];
  const float* W21 = (const float*)d_in[8];
  const float* b21 = (const float*)d_in[9];
  float* out = (float*)d_out;

  char* w = (char*)d_ws;
  int*   idx   = (int*)(w + 0);            // 147456
  int*   cur   = (int*)(w + 147456);       // 16384  (doubles as DV)
  int*   elist = (int*)(w + 163840);       // 4096*32*4 = 524288
  float* bufP  = (float*)(w + 688128);     // 4 MB
  float* bufZ  = (float*)(w + 4882432);    // 4 MB

  float* x1out = out + (size_t)N_NODES * 256;
  float* x2out = out + (size_t)N_NODES * 256 + (size_t)N_NODES * 128;

  // hypergraph construction (elist built inside topk; cur == DV afterwards)
  zero_kernel<<<16, 256, 0, stream>>>(cur);
  topk_kernel<<<N_NODES / 4, 256, 0, stream>>>(adj, idx, cur, elist);

  // layer 1 (gemm1 also emits the out=x passthrough)
  gemm_bias<256, 128, 8, true><<<N_NODES / 8, 128, 0, stream>>>(x, W10, b10, bufP, out);
  edge_gather<128><<<N_NODES, 128, 0, stream>>>(bufP, idx, cur, bufZ);
  node_gemm<128, false><<<N_NODES / 4, 256, 0, stream>>>(bufZ, elist, cur,
                                                         W11, b11, bufP, nullptr);
  edge_gather<128><<<N_NODES, 128, 0, stream>>>(bufP, idx, cur, bufZ);
  // x1 = relu(node gather); fused with layer-2 first GEMM, also writes x1out
  node_gemm<128, true><<<N_NODES / 4, 256, 0, stream>>>(bufZ, elist, cur,
                                                        W20, b20, bufP, x1out);
  // layer 2
  edge_gather<128><<<N_NODES, 128, 0, stream>>>(bufP, idx, cur, bufZ);
  node_gemm<256, false><<<N_NODES / 4, 256, 0, stream>>>(bufZ, elist, cur,
                                                         W21, b21, bufP, nullptr);
  edge_gather<256><<<N_NODES, 256, 0, stream>>>(bufP, idx, cur, bufZ);
  node_gather<256><<<N_NODES, 256, 0, stream>>>(bufZ, elist, cur, x2out);
}

// Round 9
// 128.301 us; speedup vs baseline: 1.4469x; 1.0291x over previous
//
#include <hip/hip_runtime.h>

#define N_NODES 4096
#define KNN 9
#define CAPS 128                // survivor capacity per row (2 per lane)
#define CAPE 32                 // max edges per node in strided elist
#define THRESH 0.99f

__device__ __forceinline__ bool vi_greater(float av, int aj, float bv, int bj) {
  // order: larger value first; ties -> smaller index first (matches lax.top_k)
  return (av > bv) || (av == bv && aj < bj);
}

// Zero the per-node edge counters (custom kernel: rocclr fill costs ~40us).
__global__ void zero_kernel(int* __restrict__ cur) {
  int i = blockIdx.x * blockDim.x + threadIdx.x;
  if (i < N_NODES) cur[i] = 0;
}

// Top-k: one wave per row, 4 waves/block. Branchless ballot-compaction of
// survivors (> THRESH, off-diagonal) into per-wave LDS, then 8 wave-argmax
// rounds (9th slot is always the center node). Exact full-row fallback.
// Lanes 0..8 then write idx and append this edge to each member's strided
// elist (cur doubles as the node degree DV).
__global__ __launch_bounds__(256) void topk_kernel(const float* __restrict__ dis,
                                                   int* __restrict__ idx,
                                                   int* __restrict__ cur,
                                                   int* __restrict__ elist) {
  __shared__ float sval[4 * CAPS];
  __shared__ int   sidx[4 * CAPS];
  const int lane = threadIdx.x & 63;
  const int wv = threadIdx.x >> 6;
  const int row = blockIdx.x * 4 + wv;
  const float4* r4 = reinterpret_cast<const float4*>(dis + (size_t)row * N_NODES);
  float* wval = sval + wv * CAPS;
  int*   widx = sidx + wv * CAPS;
  const unsigned long long lmask = (1ull << lane) - 1;

  // phase 1: branch-free survivor compaction
  int n = 0;
#pragma unroll 4
  for (int t = 0; t < 16; ++t) {
    float4 f4 = r4[t * 64 + lane];
    float vals[4] = {f4.x, f4.y, f4.z, f4.w};
    int cb = (t * 64 + lane) * 4;
#pragma unroll
    for (int q = 0; q < 4; ++q) {
      int cc = cb + q;
      bool pred = (vals[q] > THRESH) && (cc != row);
      unsigned long long m = __ballot(pred);
      if (pred) {
        int p = n + __popcll(m & lmask);
        if (p < CAPS) { wval[p] = vals[q]; widx[p] = cc; }
      }
      n += __popcll(m);
    }
  }
  __syncthreads();

  int outj[KNN];
  if (n >= 8 && n <= CAPS) {
    // fast path: top-8 of survivors; slot 8 is the center (diagonal zeroed in
    // the reference can never beat >=8 survivors above 0.99).
    float v0 = -3.0e38f, v1 = -3.0e38f;
    int c0 = 0x7fffffff, c1 = 0x7fffffff;
    if (lane < n)      { v0 = wval[lane];      c0 = widx[lane]; }
    if (lane + 64 < n) { v1 = wval[lane + 64]; c1 = widx[lane + 64]; }
#pragma unroll
    for (int rnd = 0; rnd < 8; ++rnd) {
      bool first = vi_greater(v0, c0, v1, c1);
      float mv = first ? v0 : v1;
      int   mc = first ? c0 : c1;
#pragma unroll
      for (int d = 1; d < 64; d <<= 1) {
        float ov = __shfl_xor(mv, d);
        int   oc = __shfl_xor(mc, d);
        if (vi_greater(ov, oc, mv, mc)) { mv = ov; mc = oc; }
      }
      outj[rnd] = mc;
      if (c0 == mc) v0 = -3.3e38f;
      if (c1 == mc) v1 = -3.3e38f;
    }
    outj[8] = row;
  } else {
    // exact fallback: full-row per-lane sorted top-9 + 9 extraction rounds
    const float* r = dis + (size_t)row * N_NODES;
    float v[9]; int ji[9];
#pragma unroll
    for (int t = 0; t < 9; ++t) { v[t] = -3.0e38f; ji[t] = 0x7fffffff; }
    for (int t = 0; t < 64; ++t) {
      int cc = t * 64 + lane;
      float val = (cc == row) ? 0.0f : r[cc];
      if (vi_greater(val, cc, v[8], ji[8])) {
        v[8] = val; ji[8] = cc;
#pragma unroll
        for (int s = 8; s > 0; --s) {
          if (vi_greater(v[s], ji[s], v[s-1], ji[s-1])) {
            float tv = v[s]; v[s] = v[s-1]; v[s-1] = tv;
            int tj = ji[s]; ji[s] = ji[s-1]; ji[s-1] = tj;
          }
        }
      }
    }
    bool has_center = false;
#pragma unroll
    for (int rnd = 0; rnd < 9; ++rnd) {
      float mv = v[0]; int mj = ji[0];
#pragma unroll
      for (int d = 1; d < 64; d <<= 1) {
        float ov = __shfl_xor(mv, d);
        int   oj = __shfl_xor(mj, d);
        if (vi_greater(ov, oj, mv, mj)) { mv = ov; mj = oj; }
      }
      outj[rnd] = mj;
      has_center = has_center || (mj == row);
      if (ji[0] == mj) {
#pragma unroll
        for (int s = 0; s < 8; ++s) { v[s] = v[s+1]; ji[s] = ji[s+1]; }
        v[8] = -3.0e38f; ji[8] = 0x7fffffff;
      }
    }
    if (!has_center) outj[8] = row;
  }

  // lanes 0..8: write idx and append edge `row` to member outj[lane]'s list.
  if (lane < KNN) {
    int j = outj[lane];
    idx[row * KNN + lane] = j;
    int p = atomicAdd(&cur[j], 1);
    if (p < CAPE) elist[j * CAPE + p] = row;
  }
}

// Stage A: Z[e,f] = (1/9) * sum_j DV[idx[e][j]]^-1/2 * Y[idx[e][j], f]
template<int F>
__global__ __launch_bounds__(F) void edge_gather(const float* __restrict__ Y,
                                                 const int* __restrict__ idx,
                                                 const int* __restrict__ DV,
                                                 float* __restrict__ Z) {
  __shared__ int er[KNN];
  __shared__ float ew[KNN];
  int e = blockIdx.x;
  if (threadIdx.x < KNN) {
    int r = idx[e * KNN + threadIdx.x];
    er[threadIdx.x] = r;
    ew[threadIdx.x] = rsqrtf((float)DV[r]);
  }
  __syncthreads();
  int f = threadIdx.x;
  float acc = 0.f;
#pragma unroll
  for (int j = 0; j < KNN; ++j)
    acc = fmaf(ew[j], Y[(size_t)er[j] * F + f], acc);
  Z[(size_t)e * F + f] = acc * (1.0f / 9.0f);
}

// Latency-flat node gather for one (row i, col f): registers hold the edge
// list (int4 loads), accumulate with compile-time-unrolled predicated chunks.
// Guards are required: unwritten elist slots hold workspace poison.
template<int KD>
__device__ __forceinline__ float node_acc(const float* __restrict__ Z,
                                          const int* __restrict__ elist,
                                          int i, int f, int cnt) {
  const int4* el4 = reinterpret_cast<const int4*>(elist + i * CAPE);
  int4 ea = el4[0], eb = el4[1];
  int e1[8] = {ea.x, ea.y, ea.z, ea.w, eb.x, eb.y, eb.z, eb.w};
  float acc = 0.f;
#pragma unroll
  for (int j = 0; j < 8; ++j)
    if (j < cnt) acc += Z[(size_t)e1[j] * KD + f];
  if (cnt > 8) {
    int4 ec = el4[2], ed = el4[3];
    int e2[8] = {ec.x, ec.y, ec.z, ec.w, ed.x, ed.y, ed.z, ed.w};
#pragma unroll
    for (int j = 0; j < 8; ++j)
      if (8 + j < cnt) acc += Z[(size_t)e2[j] * KD + f];
    for (int t = 16; t < cnt; ++t)               // rare tail (~1% of nodes)
      acc += Z[(size_t)elist[i * CAPE + t] * KD + f];
  }
  return acc;
}

// Final stage B: out[i,f] = relu(DV[i]^-1/2 * sum_{e in elist[i]} Z[e,f])
template<int F>
__global__ __launch_bounds__(F) void node_gather(const float* __restrict__ Z,
                                                 const int* __restrict__ elist,
                                                 const int* __restrict__ DV,
                                                 float* __restrict__ out) {
  int i = blockIdx.x;
  int f = threadIdx.x;
  int cnt = DV[i]; if (cnt > CAPE) cnt = CAPE;
  float acc = node_acc<F>(Z, elist, i, f, cnt);
  out[(size_t)i * F + f] = fmaxf(acc * rsqrtf((float)DV[i]), 0.f);
}

// Fused stage B + GEMM: ROWS=4, 256 threads, 1024 blocks (16 waves/CU).
// Gather phase uses the latency-flat node_acc. GEMM: FO=128: thread-half
// owns 2 rows; FO=256: thread owns all 4. Optionally writes H (x1 output).
template<int FO, bool WRITE_H>
__global__ __launch_bounds__(256) void node_gemm(const float* __restrict__ Z,
                                                 const int* __restrict__ elist,
                                                 const int* __restrict__ DV,
                                                 const float* __restrict__ W,
                                                 const float* __restrict__ bias,
                                                 float* __restrict__ P,
                                                 float* __restrict__ Hout) {
  constexpr int KD = 128;
  constexpr int ROWS = 4;
  constexpr int RPT = (FO == 128) ? 2 : 4;   // rows per thread
  __shared__ float ylds[ROWS * KD];
  int m0 = blockIdx.x * ROWS;
#pragma unroll
  for (int c0 = 0; c0 < ROWS * KD; c0 += 256) {
    int cell = c0 + threadIdx.x;
    int rr = cell >> 7, f = cell & 127;
    int i = m0 + rr;
    int cnt = DV[i]; if (cnt > CAPE) cnt = CAPE;
    float acc = node_acc<KD>(Z, elist, i, f, cnt);
    acc = fmaxf(acc * rsqrtf((float)DV[i]), 0.f);
    ylds[cell] = acc;
    if (WRITE_H) Hout[(size_t)i * KD + f] = acc;
  }
  __syncthreads();
  const int f  = (FO == 128) ? (threadIdx.x & 127) : threadIdx.x;
  const int rb = (FO == 128) ? ((threadIdx.x >> 7) * 2) : 0;
  float acc[RPT];
#pragma unroll
  for (int rr = 0; rr < RPT; ++rr) acc[rr] = 0.f;
  for (int k = 0; k < KD; k += 4) {
    float w0 = W[(size_t)(k + 0) * FO + f];
    float w1 = W[(size_t)(k + 1) * FO + f];
    float w2 = W[(size_t)(k + 2) * FO + f];
    float w3 = W[(size_t)(k + 3) * FO + f];
#pragma unroll
    for (int rr = 0; rr < RPT; ++rr) {
      float4 y = *reinterpret_cast<const float4*>(&ylds[(rb + rr) * KD + k]);
      acc[rr] = fmaf(y.x, w0, fmaf(y.y, w1, fmaf(y.z, w2, fmaf(y.w, w3, acc[rr]))));
    }
  }
  float bb = bias[f];
#pragma unroll
  for (int rr = 0; rr < RPT; ++rr)
    P[(size_t)(m0 + rb + rr) * FO + f] = acc[rr] + bb;
}

// Dense P = Y @ W + bias, node_gemm geometry: KD=256, FO=128, ROWS=4,
// 256 threads, 1024 blocks. COPY: writes staged Y rows to xcopy (x output).
template<bool COPY>
__global__ __launch_bounds__(256) void gemm_bias(const float* __restrict__ Y,
                                                 const float* __restrict__ W,
                                                 const float* __restrict__ bias,
                                                 float* __restrict__ P,
                                                 float* __restrict__ xcopy) {
  constexpr int KD = 256, FO = 128, ROWS = 4;
  __shared__ float ylds[ROWS * KD];
  int m0 = blockIdx.x * ROWS;
  for (int t = threadIdx.x; t < ROWS * KD / 4; t += 256) {
    float4 y4 = reinterpret_cast<const float4*>(Y + (size_t)m0 * KD)[t];
    reinterpret_cast<float4*>(ylds)[t] = y4;
    if (COPY) reinterpret_cast<float4*>(xcopy + (size_t)m0 * KD)[t] = y4;
  }
  __syncthreads();
  const int f  = threadIdx.x & 127;
  const int rb = (threadIdx.x >> 7) * 2;
  float acc[2] = {0.f, 0.f};
  for (int k = 0; k < KD; k += 4) {
    float w0 = W[(size_t)(k + 0) * FO + f];
    float w1 = W[(size_t)(k + 1) * FO + f];
    float w2 = W[(size_t)(k + 2) * FO + f];
    float w3 = W[(size_t)(k + 3) * FO + f];
#pragma unroll
    for (int rr = 0; rr < 2; ++rr) {
      float4 y = *reinterpret_cast<const float4*>(&ylds[(rb + rr) * KD + k]);
      acc[rr] = fmaf(y.x, w0, fmaf(y.y, w1, fmaf(y.z, w2, fmaf(y.w, w3, acc[rr]))));
    }
  }
  float bb = bias[f];
#pragma unroll
  for (int rr = 0; rr < 2; ++rr)
    P[(size_t)(m0 + rb + rr) * FO + f] = acc[rr] + bb;
}

extern "C" void kernel_launch(void* const* d_in, const int* in_sizes, int n_in,
                              void* d_out, int out_size, void* d_ws, size_t ws_size,
                              hipStream_t stream) {
  const float* x   = (const float*)d_in[0];
  const float* adj = (const float*)d_in[1];
  const float* W10 = (const float*)d_in[2];
  const float* b10 = (const float*)d_in[3];
  const float* W11 = (const float*)d_in[4];
  const float* b11 = (const float*)d_in[5];
  const float* W20 = (const float*)d_in[6];
  const float* b20 = (const float*)d_in[7];
  const float* W21 = (const float*)d_in[8];
  const float* b21 = (const float*)d_in[9];
  float* out = (float*)d_out;

  char* w = (char*)d_ws;
  int*   idx   = (int*)(w + 0);            // 147456
  int*   cur   = (int*)(w + 147456);       // 16384  (doubles as DV)
  int*   elist = (int*)(w + 163840);       // 4096*32*4 = 524288
  float* bufP  = (float*)(w + 688128);     // 4 MB
  float* bufZ  = (float*)(w + 4882432);    // 4 MB

  float* x1out = out + (size_t)N_NODES * 256;
  float* x2out = out + (size_t)N_NODES * 256 + (size_t)N_NODES * 128;

  // hypergraph construction (elist built inside topk; cur == DV afterwards)
  zero_kernel<<<16, 256, 0, stream>>>(cur);
  topk_kernel<<<N_NODES / 4, 256, 0, stream>>>(adj, idx, cur, elist);

  // layer 1 (gemm1 also emits the out=x passthrough)
  gemm_bias<true><<<N_NODES / 4, 256, 0, stream>>>(x, W10, b10, bufP, out);
  edge_gather<128><<<N_NODES, 128, 0, stream>>>(bufP, idx, cur, bufZ);
  node_gemm<128, false><<<N_NODES / 4, 256, 0, stream>>>(bufZ, elist, cur,
                                                         W11, b11, bufP, nullptr);
  edge_gather<128><<<N_NODES, 128, 0, stream>>>(bufP, idx, cur, bufZ);
  // x1 = relu(node gather); fused with layer-2 first GEMM, also writes x1out
  node_gemm<128, true><<<N_NODES / 4, 256, 0, stream>>>(bufZ, elist, cur,
                                                        W20, b20, bufP, x1out);
  // layer 2
  edge_gather<128><<<N_NODES, 128, 0, stream>>>(bufP, idx, cur, bufZ);
  node_gemm<256, false><<<N_NODES / 4, 256, 0, stream>>>(bufZ, elist, cur,
                                                         W21, b21, bufP, nullptr);
  edge_gather<256><<<N_NODES, 256, 0, stream>>>(bufP, idx, cur, bufZ);
  node_gather<256><<<N_NODES, 256, 0, stream>>>(bufZ, elist, cur, x2out);
}

// Round 10
// 108.844 us; speedup vs baseline: 1.7056x; 1.1788x over previous
//
#include <hip/hip_runtime.h>

#define N_NODES 4096
#define KNN 9
#define CAPS 128                // survivor capacity per row (2 per lane)
#define CAPE 32                 // max edges per node in strided elist
#define THRESH 0.99f

__device__ __forceinline__ bool vi_greater(float av, int aj, float bv, int bj) {
  // order: larger value first; ties -> smaller index first (matches lax.top_k)
  return (av > bv) || (av == bv && aj < bj);
}

// Zero the edge counters AND the elist (so unwritten slots are valid edge
// index 0, enabling branch-free speculative loads in node_acc).
__global__ void init_kernel(int* __restrict__ cur, int* __restrict__ elist) {
  int gid = blockIdx.x * blockDim.x + threadIdx.x;
  if (gid < N_NODES) cur[gid] = 0;
  for (int t = gid; t < N_NODES * CAPE; t += gridDim.x * blockDim.x)
    elist[t] = 0;
}

// Top-k: one wave per row, 4 waves/block. Branchless ballot-compaction of
// survivors (> THRESH, off-diagonal) into per-wave LDS, then 8 wave-argmax
// rounds (9th slot is always the center node). Exact full-row fallback.
// Lanes 0..8 then write idx and append this edge to each member's strided
// elist (cur doubles as the node degree DV).
__global__ __launch_bounds__(256) void topk_kernel(const float* __restrict__ dis,
                                                   int* __restrict__ idx,
                                                   int* __restrict__ cur,
                                                   int* __restrict__ elist) {
  __shared__ float sval[4 * CAPS];
  __shared__ int   sidx[4 * CAPS];
  const int lane = threadIdx.x & 63;
  const int wv = threadIdx.x >> 6;
  const int row = blockIdx.x * 4 + wv;
  const float4* r4 = reinterpret_cast<const float4*>(dis + (size_t)row * N_NODES);
  float* wval = sval + wv * CAPS;
  int*   widx = sidx + wv * CAPS;
  const unsigned long long lmask = (1ull << lane) - 1;

  // phase 1: branch-free survivor compaction
  int n = 0;
#pragma unroll 4
  for (int t = 0; t < 16; ++t) {
    float4 f4 = r4[t * 64 + lane];
    float vals[4] = {f4.x, f4.y, f4.z, f4.w};
    int cb = (t * 64 + lane) * 4;
#pragma unroll
    for (int q = 0; q < 4; ++q) {
      int cc = cb + q;
      bool pred = (vals[q] > THRESH) && (cc != row);
      unsigned long long m = __ballot(pred);
      if (pred) {
        int p = n + __popcll(m & lmask);
        if (p < CAPS) { wval[p] = vals[q]; widx[p] = cc; }
      }
      n += __popcll(m);
    }
  }
  __syncthreads();

  int outj[KNN];
  if (n >= 8 && n <= CAPS) {
    // fast path: top-8 of survivors; slot 8 is the center (diagonal zeroed in
    // the reference can never beat >=8 survivors above 0.99).
    float v0 = -3.0e38f, v1 = -3.0e38f;
    int c0 = 0x7fffffff, c1 = 0x7fffffff;
    if (lane < n)      { v0 = wval[lane];      c0 = widx[lane]; }
    if (lane + 64 < n) { v1 = wval[lane + 64]; c1 = widx[lane + 64]; }
#pragma unroll
    for (int rnd = 0; rnd < 8; ++rnd) {
      bool first = vi_greater(v0, c0, v1, c1);
      float mv = first ? v0 : v1;
      int   mc = first ? c0 : c1;
#pragma unroll
      for (int d = 1; d < 64; d <<= 1) {
        float ov = __shfl_xor(mv, d);
        int   oc = __shfl_xor(mc, d);
        if (vi_greater(ov, oc, mv, mc)) { mv = ov; mc = oc; }
      }
      outj[rnd] = mc;
      if (c0 == mc) v0 = -3.3e38f;
      if (c1 == mc) v1 = -3.3e38f;
    }
    outj[8] = row;
  } else {
    // exact fallback: full-row per-lane sorted top-9 + 9 extraction rounds
    const float* r = dis + (size_t)row * N_NODES;
    float v[9]; int ji[9];
#pragma unroll
    for (int t = 0; t < 9; ++t) { v[t] = -3.0e38f; ji[t] = 0x7fffffff; }
    for (int t = 0; t < 64; ++t) {
      int cc = t * 64 + lane;
      float val = (cc == row) ? 0.0f : r[cc];
      if (vi_greater(val, cc, v[8], ji[8])) {
        v[8] = val; ji[8] = cc;
#pragma unroll
        for (int s = 8; s > 0; --s) {
          if (vi_greater(v[s], ji[s], v[s-1], ji[s-1])) {
            float tv = v[s]; v[s] = v[s-1]; v[s-1] = tv;
            int tj = ji[s]; ji[s] = ji[s-1]; ji[s-1] = tj;
          }
        }
      }
    }
    bool has_center = false;
#pragma unroll
    for (int rnd = 0; rnd < 9; ++rnd) {
      float mv = v[0]; int mj = ji[0];
#pragma unroll
      for (int d = 1; d < 64; d <<= 1) {
        float ov = __shfl_xor(mv, d);
        int   oj = __shfl_xor(mj, d);
        if (vi_greater(ov, oj, mv, mj)) { mv = ov; mj = oj; }
      }
      outj[rnd] = mj;
      has_center = has_center || (mj == row);
      if (ji[0] == mj) {
#pragma unroll
        for (int s = 0; s < 8; ++s) { v[s] = v[s+1]; ji[s] = ji[s+1]; }
        v[8] = -3.0e38f; ji[8] = 0x7fffffff;
      }
    }
    if (!has_center) outj[8] = row;
  }

  // lanes 0..8: write idx and append edge `row` to member outj[lane]'s list.
  if (lane < KNN) {
    int j = outj[lane];
    idx[row * KNN + lane] = j;
    int p = atomicAdd(&cur[j], 1);
    if (p < CAPE) elist[j * CAPE + p] = row;
  }
}

// Stage A: Z[e,f] = (1/9) * sum_j DV[idx[e][j]]^-1/2 * Y[idx[e][j], f]
template<int F>
__global__ __launch_bounds__(F) void edge_gather(const float* __restrict__ Y,
                                                 const int* __restrict__ idx,
                                                 const int* __restrict__ DV,
                                                 float* __restrict__ Z) {
  __shared__ int er[KNN];
  __shared__ float ew[KNN];
  int e = blockIdx.x;
  if (threadIdx.x < KNN) {
    int r = idx[e * KNN + threadIdx.x];
    er[threadIdx.x] = r;
    ew[threadIdx.x] = rsqrtf((float)DV[r]);
  }
  __syncthreads();
  int f = threadIdx.x;
  float acc = 0.f;
#pragma unroll
  for (int j = 0; j < KNN; ++j)
    acc = fmaf(ew[j], Y[(size_t)er[j] * F + f], acc);
  Z[(size_t)e * F + f] = acc * (1.0f / 9.0f);
}

// Latency-flat node gather: 16 UNCONDITIONAL Z loads (elist pre-zeroed, so
// every slot is a valid index) masked by v_cndmask — single waitcnt ramp,
// no branches. Rare cnt>16 tail is a serial loop (~1% of nodes).
template<int KD>
__device__ __forceinline__ float node_acc(const float* __restrict__ Z,
                                          const int* __restrict__ elist,
                                          int i, int f, int cnt) {
  const int4* el4 = reinterpret_cast<const int4*>(elist + i * CAPE);
  int4 ea = el4[0], eb = el4[1], ec = el4[2], ed = el4[3];
  int e1[16] = {ea.x, ea.y, ea.z, ea.w, eb.x, eb.y, eb.z, eb.w,
                ec.x, ec.y, ec.z, ec.w, ed.x, ed.y, ed.z, ed.w};
  float acc = 0.f;
#pragma unroll
  for (int j = 0; j < 16; ++j) {
    float m = (j < cnt) ? 1.0f : 0.0f;
    acc = fmaf(m, Z[(size_t)e1[j] * KD + f], acc);
  }
  for (int t = 16; t < cnt; ++t)
    acc += Z[(size_t)elist[i * CAPE + t] * KD + f];
  return acc;
}

// Final stage B: out[i,f] = relu(DV[i]^-1/2 * sum_{e in elist[i]} Z[e,f])
template<int F>
__global__ __launch_bounds__(F) void node_gather(const float* __restrict__ Z,
                                                 const int* __restrict__ elist,
                                                 const int* __restrict__ DV,
                                                 float* __restrict__ out) {
  int i = blockIdx.x;
  int f = threadIdx.x;
  int cnt = DV[i]; if (cnt > CAPE) cnt = CAPE;
  float acc = node_acc<F>(Z, elist, i, f, cnt);
  out[(size_t)i * F + f] = fmaxf(acc * rsqrtf((float)DV[i]), 0.f);
}

// Fused stage B + GEMM: ROWS=4, 256 threads, 1024 blocks (16 waves/CU).
// Gather phase uses the branch-free node_acc. GEMM: FO=128: thread-half
// owns 2 rows; FO=256: thread owns all 4. Optionally writes H (x1 output).
template<int FO, bool WRITE_H>
__global__ __launch_bounds__(256) void node_gemm(const float* __restrict__ Z,
                                                 const int* __restrict__ elist,
                                                 const int* __restrict__ DV,
                                                 const float* __restrict__ W,
                                                 const float* __restrict__ bias,
                                                 float* __restrict__ P,
                                                 float* __restrict__ Hout) {
  constexpr int KD = 128;
  constexpr int ROWS = 4;
  constexpr int RPT = (FO == 128) ? 2 : 4;   // rows per thread
  __shared__ float ylds[ROWS * KD];
  int m0 = blockIdx.x * ROWS;
#pragma unroll
  for (int c0 = 0; c0 < ROWS * KD; c0 += 256) {
    int cell = c0 + threadIdx.x;
    int rr = cell >> 7, f = cell & 127;
    int i = m0 + rr;
    int cnt = DV[i]; if (cnt > CAPE) cnt = CAPE;
    float acc = node_acc<KD>(Z, elist, i, f, cnt);
    acc = fmaxf(acc * rsqrtf((float)DV[i]), 0.f);
    ylds[cell] = acc;
    if (WRITE_H) Hout[(size_t)i * KD + f] = acc;
  }
  __syncthreads();
  const int f  = (FO == 128) ? (threadIdx.x & 127) : threadIdx.x;
  const int rb = (FO == 128) ? ((threadIdx.x >> 7) * 2) : 0;
  float acc[RPT];
#pragma unroll
  for (int rr = 0; rr < RPT; ++rr) acc[rr] = 0.f;
  for (int k = 0; k < KD; k += 4) {
    float w0 = W[(size_t)(k + 0) * FO + f];
    float w1 = W[(size_t)(k + 1) * FO + f];
    float w2 = W[(size_t)(k + 2) * FO + f];
    float w3 = W[(size_t)(k + 3) * FO + f];
#pragma unroll
    for (int rr = 0; rr < RPT; ++rr) {
      float4 y = *reinterpret_cast<const float4*>(&ylds[(rb + rr) * KD + k]);
      acc[rr] = fmaf(y.x, w0, fmaf(y.y, w1, fmaf(y.z, w2, fmaf(y.w, w3, acc[rr]))));
    }
  }
  float bb = bias[f];
#pragma unroll
  for (int rr = 0; rr < RPT; ++rr)
    P[(size_t)(m0 + rb + rr) * FO + f] = acc[rr] + bb;
}

// Dense P = Y @ W + bias, node_gemm geometry: KD=256, FO=128, ROWS=4,
// 256 threads, 1024 blocks. COPY: writes staged Y rows to xcopy (x output).
template<bool COPY>
__global__ __launch_bounds__(256) void gemm_bias(const float* __restrict__ Y,
                                                 const float* __restrict__ W,
                                                 const float* __restrict__ bias,
                                                 float* __restrict__ P,
                                                 float* __restrict__ xcopy) {
  constexpr int KD = 256, FO = 128, ROWS = 4;
  __shared__ float ylds[ROWS * KD];
  int m0 = blockIdx.x * ROWS;
  for (int t = threadIdx.x; t < ROWS * KD / 4; t += 256) {
    float4 y4 = reinterpret_cast<const float4*>(Y + (size_t)m0 * KD)[t];
    reinterpret_cast<float4*>(ylds)[t] = y4;
    if (COPY) reinterpret_cast<float4*>(xcopy + (size_t)m0 * KD)[t] = y4;
  }
  __syncthreads();
  const int f  = threadIdx.x & 127;
  const int rb = (threadIdx.x >> 7) * 2;
  float acc[2] = {0.f, 0.f};
  for (int k = 0; k < KD; k += 4) {
    float w0 = W[(size_t)(k + 0) * FO + f];
    float w1 = W[(size_t)(k + 1) * FO + f];
    float w2 = W[(size_t)(k + 2) * FO + f];
    float w3 = W[(size_t)(k + 3) * FO + f];
#pragma unroll
    for (int rr = 0; rr < 2; ++rr) {
      float4 y = *reinterpret_cast<const float4*>(&ylds[(rb + rr) * KD + k]);
      acc[rr] = fmaf(y.x, w0, fmaf(y.y, w1, fmaf(y.z, w2, fmaf(y.w, w3, acc[rr]))));
    }
  }
  float bb = bias[f];
#pragma unroll
  for (int rr = 0; rr < 2; ++rr)
    P[(size_t)(m0 + rb + rr) * FO + f] = acc[rr] + bb;
}

extern "C" void kernel_launch(void* const* d_in, const int* in_sizes, int n_in,
                              void* d_out, int out_size, void* d_ws, size_t ws_size,
                              hipStream_t stream) {
  const float* x   = (const float*)d_in[0];
  const float* adj = (const float*)d_in[1];
  const float* W10 = (const float*)d_in[2];
  const float* b10 = (const float*)d_in[3];
  const float* W11 = (const float*)d_in[4];
  const float* b11 = (const float*)d_in[5];
  const float* W20 = (const float*)d_in[6];
  const float* b20 = (const float*)d_in[7];
  const float* W21 = (const float*)d_in[8];
  const float* b21 = (const float*)d_in[9];
  float* out = (float*)d_out;

  char* w = (char*)d_ws;
  int*   idx   = (int*)(w + 0);            // 147456
  int*   cur   = (int*)(w + 147456);       // 16384  (doubles as DV)
  int*   elist = (int*)(w + 163840);       // 4096*32*4 = 524288
  float* bufP  = (float*)(w + 688128);     // 4 MB
  float* bufZ  = (float*)(w + 4882432);    // 4 MB

  float* x1out = out + (size_t)N_NODES * 256;
  float* x2out = out + (size_t)N_NODES * 256 + (size_t)N_NODES * 128;

  // hypergraph construction (elist built inside topk; cur == DV afterwards)
  init_kernel<<<256, 256, 0, stream>>>(cur, elist);
  topk_kernel<<<N_NODES / 4, 256, 0, stream>>>(adj, idx, cur, elist);

  // layer 1 (gemm1 also emits the out=x passthrough)
  gemm_bias<true><<<N_NODES / 4, 256, 0, stream>>>(x, W10, b10, bufP, out);
  edge_gather<128><<<N_NODES, 128, 0, stream>>>(bufP, idx, cur, bufZ);
  node_gemm<128, false><<<N_NODES / 4, 256, 0, stream>>>(bufZ, elist, cur,
                                                         W11, b11, bufP, nullptr);
  edge_gather<128><<<N_NODES, 128, 0, stream>>>(bufP, idx, cur, bufZ);
  // x1 = relu(node gather); fused with layer-2 first GEMM, also writes x1out
  node_gemm<128, true><<<N_NODES / 4, 256, 0, stream>>>(bufZ, elist, cur,
                                                        W20, b20, bufP, x1out);
  // layer 2
  edge_gather<128><<<N_NODES, 128, 0, stream>>>(bufP, idx, cur, bufZ);
  node_gemm<256, false><<<N_NODES / 4, 256, 0, stream>>>(bufZ, elist, cur,
                                                         W21, b21, bufP, nullptr);
  edge_gather<256><<<N_NODES, 256, 0, stream>>>(bufP, idx, cur, bufZ);
  node_gather<256><<<N_NODES, 256, 0, stream>>>(bufZ, elist, cur, x2out);
}